// Round 3
// baseline (222.261 us; speedup 1.0000x reference)
//
#include <hip/hip_runtime.h>
#include <hip/hip_bf16.h>

// AtomPoolingLayer: M=512 molecules, N=128 atoms, F=512 features, HID=128.
// Inputs fp32, OUTPUT fp32 (round-2 error fingerprint: packed-bf16 store read
// as fp32 gave exactly the EVT-predicted 4.97-sigma error of ref[2f]-ref[2f+1]).
// out[m,f] = sum_n sigmoid(relu(h[m,n,:]@W1+b1)@W2+b2) * h[m,n,f]
//
//   kernel 1: W1 fp32 [512,128] -> W1T bf16 [128,512] in d_ws (transpose+cvt)
//   kernel 2: one block per molecule; phase 1 = gate GEMM via
//             mfma_f32_16x16x32_bf16 (h truncated fp32->bf16 on the fly),
//             phase 2 = fp32 weighted feature sum, fp32 store.

typedef unsigned short u16;
typedef unsigned int u32;
typedef __bf16 bf16x8 __attribute__((ext_vector_type(8)));
typedef float f32x4 __attribute__((ext_vector_type(4)));
typedef float f32x2 __attribute__((ext_vector_type(2)));
typedef u32 u32x4 __attribute__((ext_vector_type(4)));

#define M_MOL 512
#define N_ATOM 128
#define F_DIM 512
#define HID_DIM 128

static __device__ __forceinline__ u16 f2bf(float x) {
  u32 u = __float_as_uint(x);
  u32 r = (u + 0x7fffu + ((u >> 16) & 1u)) >> 16;  // RNE
  return (u16)r;
}
static __device__ __forceinline__ bf16x8 load8bf(const u16* p) {
  u32x4 v = *(const u32x4*)p;  // 16B aligned by construction
  return __builtin_bit_cast(bf16x8, v);
}
// 8 consecutive fp32 -> bf16x8 by truncation (|rel err| <= 2^-8; gate tolerance ~2%)
static __device__ __forceinline__ bf16x8 cvt8(const float* p) {
  u32x4 a = *(const u32x4*)p;
  u32x4 b = *(const u32x4*)(p + 4);
  u32x4 r;
  r[0] = (a[0] >> 16) | (a[1] & 0xffff0000u);
  r[1] = (a[2] >> 16) | (a[3] & 0xffff0000u);
  r[2] = (b[0] >> 16) | (b[1] & 0xffff0000u);
  r[3] = (b[2] >> 16) | (b[3] & 0xffff0000u);
  return __builtin_bit_cast(bf16x8, r);
}

// ---- Kernel 1: W1 fp32 [F=512][HID=128] -> W1T bf16 [HID=128][F=512] ----
__global__ __launch_bounds__(256) void transpose_w1(const float* __restrict__ W1,
                                                    u16* __restrict__ W1T) {
  __shared__ float tile[64][65];  // +1 pad breaks bank conflicts
  const int k0 = blockIdx.x * 64;  // 8 blocks along F
  const int n0 = blockIdx.y * 64;  // 2 blocks along HID
  const int t = threadIdx.x;
  #pragma unroll
  for (int i = 0; i < 16; ++i) {
    const int lin = i * 256 + t;
    const int lr = lin >> 6, lc = lin & 63;     // lr: k within tile, lc: n
    tile[lc][lr] = W1[(size_t)(k0 + lr) * HID_DIM + (n0 + lc)];
  }
  __syncthreads();
  #pragma unroll
  for (int i = 0; i < 16; ++i) {
    const int lin = i * 256 + t;
    const int wr = lin >> 6, wc = lin & 63;     // wr: n within tile, wc: k
    W1T[(size_t)(n0 + wr) * F_DIM + (k0 + wc)] = f2bf(tile[wr][wc]);
  }
}

// ---- Kernel 2: fused gate + weighted pooling, one block per molecule ----
__global__ __launch_bounds__(256) void atom_pool_kernel(
    const float* __restrict__ h, const u16* __restrict__ W1T,
    const float* __restrict__ b1, const float* __restrict__ W2,
    const float* __restrict__ b2, float* __restrict__ out) {
  const int m = blockIdx.x;
  const int tid = threadIdx.x;
  const int wv = tid >> 6;       // wave 0..3
  const int lane = tid & 63;
  const int quad = lane >> 4;    // 0..3
  const int cl = lane & 15;      // 0..15

  __shared__ float w_s[N_ATOM];        // gate weights per atom
  __shared__ float red[4][F_DIM];      // cross-wave reduction buffer

  const float* hm = h + (size_t)m * N_ATOM * F_DIM;

  // ===== Phase 1: T[atom][hid] = h[m] @ W1; MFMA 16x16x32 bf16 =====
  // A-frag: A[m=cl][k=quad*8+j]  -> h row (fp32->bf16 truncate)
  // B-frag: B[k=quad*8+j][n=cl]  -> W1T row (contiguous 16B)
  // C: row(atom)=quad*4+reg, col(hid)=cl
  f32x4 acc[2][8];
  #pragma unroll
  for (int s = 0; s < 2; ++s)
    #pragma unroll
    for (int t = 0; t < 8; ++t)
      acc[s][t] = (f32x4){0.f, 0.f, 0.f, 0.f};

  const int strip0 = wv * 2;  // each wave: atom strips [strip0, strip0+1]
  const float* arow0 = hm + (size_t)(strip0 * 16 + cl) * F_DIM;
  const float* arow1 = arow0 + 16 * F_DIM;
  const int kb = quad * 8;

  #pragma unroll 2
  for (int ks = 0; ks < 16; ++ks) {
    const int k = ks * 32 + kb;
    bf16x8 a0 = cvt8(arow0 + k);
    bf16x8 a1 = cvt8(arow1 + k);
    #pragma unroll
    for (int t = 0; t < 8; ++t) {
      bf16x8 bfr = load8bf(W1T + (size_t)(t * 16 + cl) * F_DIM + k);
      acc[0][t] = __builtin_amdgcn_mfma_f32_16x16x32_bf16(a0, bfr, acc[0][t], 0, 0, 0);
      acc[1][t] = __builtin_amdgcn_mfma_f32_16x16x32_bf16(a1, bfr, acc[1][t], 0, 0, 0);
    }
  }

  // Epilogue: relu(T + b1) @ W2, sigmoid -> w_s[atom]
  float psum[2][4] = {{0.f, 0.f, 0.f, 0.f}, {0.f, 0.f, 0.f, 0.f}};
  #pragma unroll
  for (int t = 0; t < 8; ++t) {
    const int hid = t * 16 + cl;
    const float b1v = b1[hid];
    const float w2v = W2[hid];
    #pragma unroll
    for (int s = 0; s < 2; ++s)
      #pragma unroll
      for (int r = 0; r < 4; ++r) {
        float tv = acc[s][t][r] + b1v;
        tv = fmaxf(tv, 0.f);
        psum[s][r] = fmaf(tv, w2v, psum[s][r]);
      }
  }
  // reduce across the 16 hid-columns held by lanes cl=0..15 (same quad = same atoms)
  #pragma unroll
  for (int off = 1; off < 16; off <<= 1) {
    #pragma unroll
    for (int s = 0; s < 2; ++s)
      #pragma unroll
      for (int r = 0; r < 4; ++r)
        psum[s][r] += __shfl_xor(psum[s][r], off, 64);
  }
  if (cl == 0) {
    const float b2v = b2[0];
    #pragma unroll
    for (int s = 0; s < 2; ++s)
      #pragma unroll
      for (int r = 0; r < 4; ++r) {
        const int atom = (strip0 + s) * 16 + quad * 4 + r;
        const float x = psum[s][r] + b2v;
        w_s[atom] = 1.f / (1.f + __expf(-x));
      }
  }
  __syncthreads();

  // ===== Phase 2: out[m][f] = sum_n w_s[n] * h[m][n][f] (fp32) =====
  float facc[8] = {0.f, 0.f, 0.f, 0.f, 0.f, 0.f, 0.f, 0.f};
  const int f0 = lane * 8;                  // each lane owns 8 consecutive features
  const float* hrow = hm + (size_t)(wv * 32) * F_DIM + f0;  // wave owns 32 atoms
  #pragma unroll 4
  for (int i = 0; i < 32; ++i) {
    const float wn = w_s[wv * 32 + i];      // LDS broadcast
    f32x4 h0 = *(const f32x4*)(hrow + (size_t)i * F_DIM);
    f32x4 h1 = *(const f32x4*)(hrow + (size_t)i * F_DIM + 4);
    #pragma unroll
    for (int j = 0; j < 4; ++j) {
      facc[j]     = fmaf(wn, h0[j], facc[j]);
      facc[j + 4] = fmaf(wn, h1[j], facc[j + 4]);
    }
  }
  #pragma unroll
  for (int j = 0; j < 8; ++j) red[wv][f0 + j] = facc[j];
  __syncthreads();

  {
    const int f = tid * 2;  // 256 threads x 2 features = 512
    f32x2 o;
    o[0] = red[0][f] + red[1][f] + red[2][f] + red[3][f];
    o[1] = red[0][f + 1] + red[1][f + 1] + red[2][f + 1] + red[3][f + 1];
    *(f32x2*)(out + (size_t)m * F_DIM + f) = o;   // fp32 store
  }
}

extern "C" void kernel_launch(void* const* d_in, const int* in_sizes, int n_in,
                              void* d_out, int out_size, void* d_ws, size_t ws_size,
                              hipStream_t stream) {
  const float* h  = (const float*)d_in[0];   // [512,128,512] fp32
  const float* W1 = (const float*)d_in[1];   // [512,128] fp32
  const float* b1 = (const float*)d_in[2];   // [128] fp32
  const float* W2 = (const float*)d_in[3];   // [128,1] fp32
  const float* b2 = (const float*)d_in[4];   // [1] fp32
  float* out = (float*)d_out;                // [512,512] fp32
  u16* W1T = (u16*)d_ws;                     // 128 KiB scratch (rewritten every call)

  transpose_w1<<<dim3(8, 2), 256, 0, stream>>>(W1, W1T);
  atom_pool_kernel<<<M_MOL, 256, 0, stream>>>(h, W1T, b1, W2, b2, out);
}